// Round 17
// baseline (443.708 us; speedup 1.0000x reference)
//
#include <hip/hip_runtime.h>
#include <hip/hip_bf16.h>
#include <stdint.h>

#define NTILES 4
#define DMODEL 1024
#define DFF    4096
#define NTOK   16384

typedef __bf16 bf16x8 __attribute__((ext_vector_type(8)));
typedef float  f32x4  __attribute__((ext_vector_type(4)));

__device__ __forceinline__ uint16_t f2bf(float f) {
    union { float f; uint32_t u; } v; v.f = f;
    uint32_t u = v.u;
    uint32_t r = (u + 0x7fffu + ((u >> 16) & 1u)) >> 16;
    return (uint16_t)r;
}

#define STG(gptr, ldsoff) __builtin_amdgcn_global_load_lds( \
    (__attribute__((address_space(1))) void*)(gptr), \
    (__attribute__((address_space(3))) void*)(smem + (ldsoff)), 16, 0, 0)

// ---------------- lean signature reduction: Wup column partial sums ----------------
__global__ void k_sig(const float* __restrict__ Wup, double* __restrict__ partial) {
    int e = blockIdx.y, fb = blockIdx.x, tid = threadIdx.x;
    const float* src = Wup + (size_t)e * DFF * DMODEL + (size_t)fb * 64 * DMODEL + tid * 4;
    double s0 = 0, s1 = 0, s2 = 0, s3 = 0;
    #pragma unroll 4
    for (int i = 0; i < 64; ++i) {
        float4 v = *(const float4*)(src + (size_t)i * DMODEL);
        s0 += v.x; s1 += v.y; s2 += v.z; s3 += v.w;
    }
    double* p = partial + (size_t)fb * (NTILES * DMODEL) + e * DMODEL + tid * 4;
    p[0] = s0; p[1] = s1; p[2] = s2; p[3] = s3;
}

__global__ void k_sigfin(const double* __restrict__ partial, float* __restrict__ sig,
                         int* __restrict__ counts) {
    int gid = blockIdx.x * 256 + threadIdx.x;
    double s = 0.0;
    #pragma unroll 8
    for (int fb = 0; fb < 64; ++fb) s += partial[(size_t)fb * (NTILES * DMODEL) + gid];
    sig[gid] = (s > 0.0) ? 1.0f : ((s < 0.0) ? -1.0f : 0.0f);
    if (gid < NTILES) counts[gid] = 0;
}

// ---------------- routing: 64 tok/block, 4 atomics/block + fused Wup convert ----------------
__global__ void __launch_bounds__(256) k_route(const float* __restrict__ x,
                                               const float* __restrict__ sig,
                                               uint16_t* __restrict__ xb,
                                               float* __restrict__ gate_out,
                                               int* __restrict__ counts,
                                               int* __restrict__ perm,
                                               const float* __restrict__ Wup,
                                               uint16_t* __restrict__ wupb) {
    if (blockIdx.x >= NTOK / 64) {
        int cb = blockIdx.x - NTOK / 64;
        const float* src = Wup + (size_t)cb * 16384 + threadIdx.x * 4;
        uint16_t*    dst = wupb + (size_t)cb * 16384 + threadIdx.x * 4;
        #pragma unroll 4
        for (int i = 0; i < 16; ++i) {
            float4 v = *(const float4*)(src + i * 1024);
            ushort4 h;
            h.x = f2bf(v.x); h.y = f2bf(v.y); h.z = f2bf(v.z); h.w = f2bf(v.w);
            *(ushort4*)(dst + i * 1024) = h;
        }
        return;
    }
    __shared__ float sl[NTILES * DMODEL];
    __shared__ int winners[64];
    for (int i = threadIdx.x; i < NTILES * DMODEL; i += 256) sl[i] = sig[i];
    __syncthreads();
    int wave = threadIdx.x >> 6, lane = threadIdx.x & 63;
    #pragma unroll 1
    for (int tk = 0; tk < 16; ++tk) {
        int ti  = wave * 16 + tk;
        int tok = blockIdx.x * 64 + ti;
        const float* xr = x + (size_t)tok * DMODEL;
        float sc[NTILES] = {0.f, 0.f, 0.f, 0.f};
        for (int q = 0; q < 4; ++q) {
            int c = q * 256 + lane * 4;
            float4 xv = *(const float4*)(xr + c);
            #pragma unroll
            for (int t = 0; t < NTILES; ++t) {
                const float* st = sl + t * DMODEL + c;
                sc[t] += xv.x * st[0] + xv.y * st[1] + xv.z * st[2] + xv.w * st[3];
            }
            ushort4 h;
            h.x = f2bf(xv.x); h.y = f2bf(xv.y); h.z = f2bf(xv.z); h.w = f2bf(xv.w);
            *(ushort4*)(xb + (size_t)tok * DMODEL + c) = h;
        }
        #pragma unroll
        for (int t = 0; t < NTILES; ++t)
            for (int off = 32; off; off >>= 1) sc[t] += __shfl_xor(sc[t], off);
        int w = 0; float best = sc[0];
        if (sc[1] > best) { best = sc[1]; w = 1; }
        if (sc[2] > best) { best = sc[2]; w = 2; }
        if (sc[3] > best) { best = sc[3]; w = 3; }
        if (lane < NTILES) gate_out[(size_t)tok * NTILES + lane] = (lane == w) ? 1.0f : 0.0f;
        if (lane == 0) winners[ti] = w;
    }
    __syncthreads();
    if (wave == 0) {
        int w = winners[lane];
        int tok0 = blockIdx.x * 64;
        #pragma unroll
        for (int e = 0; e < NTILES; ++e) {
            unsigned long long m = __ballot(w == e);
            int my  = __popcll(m & ((1ull << lane) - 1ull));
            int tot = __popcll(m);
            int base = 0;
            if (lane == 0 && tot) base = atomicAdd(&counts[e], tot);
            base = __shfl(base, 0);
            if (w == e) perm[e * NTOK + base + my] = tok0 + lane;
        }
    }
}

// ---------------- grouped NT GEMM: 256x256, BK=64, 8-phase counted-vmcnt schedule ----------
// 512 thr = 8 waves (2M x 4N), per-wave C 128x64 (acc[8][4]); A-row map m-interleaved:
// tile_row = (m>>2)*128 + wr*64 + (m&3)*16.  LDS 128KB = 2 bufs x {A0,A1,B0,B1}[128x64].
// Per K-tile: 4 phases = quadrants (mh,ks); bF (8 frags) bulk-read at (0,0); aF (4) per phase.
// Staging: 1 half-tile (2 STG) per phase, order [B0,A0,B1,A1] at p2..p5 / p6..p8,p1';
// every overwrite is >=1 barrier after its half's last read (race-free by construction).
// vmcnt(6) ONLY at phases 4 and 8 (last iter: vmcnt(0) at p4, none at p8).
// Swizzle (R2/R8-verified, 128B rows): phys = logical ^ ((row&7)<<4); staged via
// inverse-swizzled source granule.
#define WAITV6 asm volatile("s_waitcnt vmcnt(6)" ::: "memory")
#define WAITV0 asm volatile("s_waitcnt vmcnt(0)" ::: "memory")

#define ST_A(H, KT) do { \
    STG(aP[H][0] + (size_t)(KT) * 64, (((KT) & 1) << 16) + (H) * 16384 + wid * 1024); \
    STG(aP[H][1] + (size_t)(KT) * 64, (((KT) & 1) << 16) + (H) * 16384 + 8192 + wid * 1024); \
} while (0)
#define ST_B(H, KT) do { \
    STG(bP[H][0] + (size_t)(KT) * 64, (((KT) & 1) << 16) + 32768 + (H) * 16384 + wid * 1024); \
    STG(bP[H][1] + (size_t)(KT) * 64, (((KT) & 1) << 16) + 32768 + (H) * 16384 + 8192 + wid * 1024); \
} while (0)

#define PHASE(KT, MH, KS, STAGE, WAIT) do { \
    const int _buf = ((KT) & 1) << 16; \
    bf16x8 aF[4]; \
    if ((MH) == 0 && (KS) == 0) { \
        _Pragma("unroll") \
        for (int n = 0; n < 4; ++n) { \
            bF[n][0] = *(const bf16x8*)(smem + _buf + bOff + n * 2048 + g0); \
            bF[n][1] = *(const bf16x8*)(smem + _buf + bOff + n * 2048 + g1); \
        } \
    } \
    _Pragma("unroll") \
    for (int m = 0; m < 4; ++m) \
        aF[m] = *(const bf16x8*)(smem + _buf + (MH) * 16384 + aRowOff + m * 2048 + ((KS) ? g1 : g0)); \
    STAGE; \
    __builtin_amdgcn_s_barrier(); \
    asm volatile("s_waitcnt lgkmcnt(0)" ::: "memory"); \
    __builtin_amdgcn_sched_barrier(0); \
    __builtin_amdgcn_s_setprio(1); \
    _Pragma("unroll") \
    for (int m = 0; m < 4; ++m) \
        _Pragma("unroll") \
        for (int n = 0; n < 4; ++n) \
            acc[(MH) * 4 + m][n] = __builtin_amdgcn_mfma_f32_16x16x32_bf16(aF[m], bF[n][KS], acc[(MH) * 4 + m][n], 0, 0, 0); \
    __builtin_amdgcn_s_setprio(0); \
    WAIT; \
    __builtin_amdgcn_sched_barrier(0); \
    __builtin_amdgcn_s_barrier(); \
} while (0)

template <int K, bool UP>
__global__ void __launch_bounds__(512, 1)
k_ffn8p(const uint16_t* __restrict__ A, const uint16_t* __restrict__ Bw,
        const int* __restrict__ counts, const int* __restrict__ perm,
        uint16_t* __restrict__ hid_out, float* __restrict__ out,
        const float* __restrict__ cvtSrc, uint16_t* __restrict__ cvtDst) {
    constexpr int NOUT = UP ? DFF : DMODEL;
    constexpr int NKT = K / 64;
    constexpr int NITER = NKT / 2;
    extern __shared__ char smem[];

    if constexpr (UP) {
        if (blockIdx.y >= 64) {   // fused Wdown fp32->bf16 convert
            int chunk = ((int)(blockIdx.z * 32 + (blockIdx.y - 64))) * 16 + blockIdx.x;
            const float* src = cvtSrc + (size_t)chunk * 8192 + threadIdx.x * 4;
            uint16_t*    dst = cvtDst + (size_t)chunk * 8192 + threadIdx.x * 4;
            #pragma unroll
            for (int i = 0; i < 4; ++i) {
                float4 v = *(const float4*)(src + i * 2048);
                ushort4 h;
                h.x = f2bf(v.x); h.y = f2bf(v.y); h.z = f2bf(v.z); h.w = f2bf(v.w);
                *(ushort4*)(dst + i * 2048) = h;
            }
            return;
        }
    }

    const int e = blockIdx.z;
    const int c0 = counts[0], c1 = counts[1], c2 = counts[2];
    const int cnt = counts[e];
    const int cofs = (e > 0 ? c0 : 0) + (e > 1 ? c1 : 0) + (e > 2 ? c2 : 0);
    const int base = blockIdx.y * 256;
    if (base >= cnt) return;
    const int bn0 = blockIdx.x * 256;
    const int tid = threadIdx.x;
    const int lane = tid & 63, wid = tid >> 6;
    const int wr = wid >> 2, wc = wid & 3;
    const int* permE = perm + e * NTOK;

    // ---- staging decode: thread -> (row-in-64 srow8, phys granule tid&7)
    const int srow8 = tid >> 3;
    const int sg8   = (tid & 7) ^ (srow8 & 7);     // inverse-swizzled source granule
    const uint16_t* aP[2][2];
    const uint16_t* bP[2][2];
    #pragma unroll
    for (int h = 0; h < 2; ++h)
        #pragma unroll
        for (int j = 0; j < 2; ++j) {
            int tr = h * 128 + j * 64 + srow8;
            int rr = base + tr;
            if constexpr (UP) {
                int tok = permE[(rr < cnt) ? rr : base];
                aP[h][j] = A + (size_t)tok * K + sg8 * 8;
            } else {
                aP[h][j] = A + (size_t)(cofs + rr) * K + sg8 * 8;
            }
            bP[h][j] = Bw + ((size_t)e * NOUT + bn0 + tr) * K + sg8 * 8;
        }

    // ---- fragment read constants (verified swizzle)
    const int g0 = (((lane >> 4) ^ (lane & 7)) << 4);
    const int g1 = g0 ^ 64;
    const int aRowOff = (wr * 64 + (lane & 15)) * 128;                        // + mh*16384 + m*2048
    const int bOff = 32768 + (wc >> 1) * 16384 + ((wc & 1) * 64 + (lane & 15)) * 128;  // + n*2048

    f32x4 acc[8][4];
    #pragma unroll
    for (int m = 0; m < 8; ++m)
        #pragma unroll
        for (int n = 0; n < 4; ++n) acc[m][n] = (f32x4){0.f, 0.f, 0.f, 0.f};
    bf16x8 bF[4][2];

    // prologue: kt0 {B0,A0,B1,A1}, kt1 {B0,A0,B1}; vmcnt(6) -> kt0 landed
    ST_B(0, 0); ST_A(0, 0); ST_B(1, 0); ST_A(1, 0);
    ST_B(0, 1); ST_A(0, 1); ST_B(1, 1);
    WAITV6;
    __builtin_amdgcn_sched_barrier(0);
    __builtin_amdgcn_s_barrier();

    #pragma unroll 1
    for (int i = 0; i < NITER; ++i) {
        const int k0 = 2 * i, k1 = 2 * i + 1;
        const bool pre = (i + 1) < NITER;
        PHASE(k0, 0, 0, { ST_A(1, k1); }, {});
        PHASE(k0, 0, 1, { if (pre) ST_B(0, k0 + 2); }, {});
        PHASE(k0, 1, 0, { if (pre) ST_A(0, k0 + 2); }, {});
        PHASE(k0, 1, 1, { if (pre) ST_B(1, k0 + 2); },
              { if (pre) { WAITV6; } else { WAITV0; } });
        PHASE(k1, 0, 0, { if (pre) ST_A(1, k0 + 2); }, {});
        PHASE(k1, 0, 1, { if (pre) ST_B(0, k1 + 2); }, {});
        PHASE(k1, 1, 0, { if (pre) ST_A(0, k1 + 2); }, {});
        PHASE(k1, 1, 1, { if (pre) ST_B(1, k1 + 2); },
              { if (pre) { WAITV6; } });
    }

    // epilogue: tile_row = (m>>2)*128 + wr*64 + (m&3)*16 + (lane>>4)*4 + i
    #pragma unroll
    for (int m = 0; m < 8; ++m) {
        #pragma unroll
        for (int i = 0; i < 4; ++i) {
            int r  = (m >> 2) * 128 + wr * 64 + (m & 3) * 16 + (lane >> 4) * 4 + i;
            int rr = base + r;
            if (rr < cnt) {
                if constexpr (UP) {
                    uint16_t* hr = hid_out + (size_t)(cofs + rr) * DFF + bn0 + wc * 64;
                    #pragma unroll
                    for (int n = 0; n < 4; ++n) {
                        float v = acc[m][n][i];
                        v = v > 0.f ? v : 0.f;
                        hr[n * 16 + (lane & 15)] = f2bf(v);
                    }
                } else {
                    float* orow = out + (size_t)permE[rr] * DMODEL + bn0 + wc * 64;
                    #pragma unroll
                    for (int n = 0; n < 4; ++n)
                        orow[n * 16 + (lane & 15)] = acc[m][n][i];
                }
            }
        }
    }
}

extern "C" void kernel_launch(void* const* d_in, const int* in_sizes, int n_in,
                              void* d_out, int out_size, void* d_ws, size_t ws_size,
                              hipStream_t stream) {
    const float* x     = (const float*)d_in[0];
    const float* Wup   = (const float*)d_in[1];
    const float* Wdown = (const float*)d_in[2];
    float* out  = (float*)d_out;
    float* gate = out + (size_t)NTOK * DMODEL;

    char* ws = (char*)d_ws;
    size_t off = 0;
    auto alloc = [&](size_t bytes) -> void* {
        void* p = ws + off;
        off += (bytes + 255) & ~(size_t)255;
        return p;
    };
    int*      counts  = (int*)alloc(NTILES * sizeof(int));
    float*    sig     = (float*)alloc((size_t)NTILES * DMODEL * sizeof(float));
    double*   partial = (double*)alloc((size_t)64 * NTILES * DMODEL * sizeof(double));
    int*      perm    = (int*)alloc((size_t)NTILES * NTOK * sizeof(int));
    uint16_t* xb      = (uint16_t*)alloc((size_t)NTOK * DMODEL * 2);
    uint16_t* wupb    = (uint16_t*)alloc((size_t)NTILES * DFF * DMODEL * 2);
    uint16_t* wdownb  = (uint16_t*)alloc((size_t)NTILES * DMODEL * DFF * 2);
    uint16_t* hidden  = (uint16_t*)alloc(((size_t)NTOK + 1024) * DFF * 2);
    if (off > ws_size) return;

    hipFuncSetAttribute((const void*)&k_ffn8p<DMODEL, true>,
                        hipFuncAttributeMaxDynamicSharedMemorySize, 131072);
    hipFuncSetAttribute((const void*)&k_ffn8p<DFF, false>,
                        hipFuncAttributeMaxDynamicSharedMemorySize, 131072);

    hipLaunchKernelGGL(k_sig, dim3(64, 4), dim3(256), 0, stream, Wup, partial);
    hipLaunchKernelGGL(k_sigfin, dim3(16), dim3(256), 0, stream, partial, sig, counts);
    // route (256 blocks) + fused Wup->bf16 convert (1024 blocks)
    hipLaunchKernelGGL(k_route, dim3(1280), dim3(256), 0, stream,
                       x, sig, xb, gate, counts, perm, Wup, wupb);
    // UP GEMM (y<64) + fused Wdown convert (y in [64,96) -> 2048 chunks)
    hipLaunchKernelGGL((k_ffn8p<DMODEL, true>), dim3(DFF / 256, 96, NTILES),
                       dim3(512), 131072, stream, xb, wupb, counts, perm, hidden, nullptr,
                       Wdown, wdownb);
    hipLaunchKernelGGL((k_ffn8p<DFF, false>), dim3(DMODEL / 256, 64, NTILES),
                       dim3(512), 131072, stream, hidden, wdownb, counts, perm, nullptr, out,
                       nullptr, nullptr);
}

// Round 18
// 431.860 us; speedup vs baseline: 1.0274x; 1.0274x over previous
//
#include <hip/hip_runtime.h>
#include <hip/hip_bf16.h>
#include <stdint.h>

#define NTILES 4
#define DMODEL 1024
#define DFF    4096
#define NTOK   16384
#define YGEMM  128      // UP grid: y<128 GEMM, y>=128 Wdown-convert chunks

typedef __bf16 bf16x8 __attribute__((ext_vector_type(8)));
typedef float  f32x4  __attribute__((ext_vector_type(4)));

__device__ __forceinline__ uint16_t f2bf(float f) {
    union { float f; uint32_t u; } v; v.f = f;
    uint32_t u = v.u;
    uint32_t r = (u + 0x7fffu + ((u >> 16) & 1u)) >> 16;
    return (uint16_t)r;
}

#define STG(gptr, ldsoff) __builtin_amdgcn_global_load_lds( \
    (__attribute__((address_space(1))) void*)(gptr), \
    (__attribute__((address_space(3))) void*)(smem + (ldsoff)), 16, 0, 0)

// ---------------- lean signature reduction: Wup column partial sums ----------------
__global__ void k_sig(const float* __restrict__ Wup, double* __restrict__ partial) {
    int e = blockIdx.y, fb = blockIdx.x, tid = threadIdx.x;
    const float* src = Wup + (size_t)e * DFF * DMODEL + (size_t)fb * 64 * DMODEL + tid * 4;
    double s0 = 0, s1 = 0, s2 = 0, s3 = 0;
    #pragma unroll 4
    for (int i = 0; i < 64; ++i) {
        float4 v = *(const float4*)(src + (size_t)i * DMODEL);
        s0 += v.x; s1 += v.y; s2 += v.z; s3 += v.w;
    }
    double* p = partial + (size_t)fb * (NTILES * DMODEL) + e * DMODEL + tid * 4;
    p[0] = s0; p[1] = s1; p[2] = s2; p[3] = s3;
}

// signature finalize (coalesced) + zero expert counts
__global__ void k_sigfin(const double* __restrict__ partial, float* __restrict__ sig,
                         int* __restrict__ counts) {
    int gid = blockIdx.x * 256 + threadIdx.x;    // 0..4095
    double s = 0.0;
    #pragma unroll 8
    for (int fb = 0; fb < 64; ++fb) s += partial[(size_t)fb * (NTILES * DMODEL) + gid];
    sig[gid] = (s > 0.0) ? 1.0f : ((s < 0.0) ? -1.0f : 0.0f);
    if (gid < NTILES) counts[gid] = 0;
}

// ---------------- routing: 64 tok/block, 4 atomics/block (ballot prefix) ----------------
// blockIdx.x < 256: route; >= 256: Wup->bf16 convert chunk (streams overlap).
__global__ void __launch_bounds__(256) k_route(const float* __restrict__ x,
                                               const float* __restrict__ sig,
                                               uint16_t* __restrict__ xb,
                                               float* __restrict__ gate_out,
                                               int* __restrict__ counts,
                                               int* __restrict__ perm,
                                               const float* __restrict__ Wup,
                                               uint16_t* __restrict__ wupb) {
    if (blockIdx.x >= NTOK / 64) {
        int cb = blockIdx.x - NTOK / 64;         // 0..1023, 16384 elems each
        const float* src = Wup + (size_t)cb * 16384 + threadIdx.x * 4;
        uint16_t*    dst = wupb + (size_t)cb * 16384 + threadIdx.x * 4;
        #pragma unroll 4
        for (int i = 0; i < 16; ++i) {
            float4 v = *(const float4*)(src + i * 1024);
            ushort4 h;
            h.x = f2bf(v.x); h.y = f2bf(v.y); h.z = f2bf(v.z); h.w = f2bf(v.w);
            *(ushort4*)(dst + i * 1024) = h;
        }
        return;
    }
    __shared__ float sl[NTILES * DMODEL];
    __shared__ int winners[64];
    for (int i = threadIdx.x; i < NTILES * DMODEL; i += 256) sl[i] = sig[i];
    __syncthreads();
    int wave = threadIdx.x >> 6, lane = threadIdx.x & 63;
    #pragma unroll 1
    for (int tk = 0; tk < 16; ++tk) {
        int ti  = wave * 16 + tk;
        int tok = blockIdx.x * 64 + ti;
        const float* xr = x + (size_t)tok * DMODEL;
        float sc[NTILES] = {0.f, 0.f, 0.f, 0.f};
        for (int q = 0; q < 4; ++q) {
            int c = q * 256 + lane * 4;
            float4 xv = *(const float4*)(xr + c);
            #pragma unroll
            for (int t = 0; t < NTILES; ++t) {
                const float* st = sl + t * DMODEL + c;
                sc[t] += xv.x * st[0] + xv.y * st[1] + xv.z * st[2] + xv.w * st[3];
            }
            ushort4 h;
            h.x = f2bf(xv.x); h.y = f2bf(xv.y); h.z = f2bf(xv.z); h.w = f2bf(xv.w);
            *(ushort4*)(xb + (size_t)tok * DMODEL + c) = h;
        }
        #pragma unroll
        for (int t = 0; t < NTILES; ++t)
            for (int off = 32; off; off >>= 1) sc[t] += __shfl_xor(sc[t], off);
        int w = 0; float best = sc[0];
        if (sc[1] > best) { best = sc[1]; w = 1; }
        if (sc[2] > best) { best = sc[2]; w = 2; }
        if (sc[3] > best) { best = sc[3]; w = 3; }
        if (lane < NTILES) gate_out[(size_t)tok * NTILES + lane] = (lane == w) ? 1.0f : 0.0f;
        if (lane == 0) winners[ti] = w;
    }
    __syncthreads();
    if (wave == 0) {
        int w = winners[lane];
        int tok0 = blockIdx.x * 64;
        #pragma unroll
        for (int e = 0; e < NTILES; ++e) {
            unsigned long long m = __ballot(w == e);
            int my  = __popcll(m & ((1ull << lane) - 1ull));
            int tot = __popcll(m);
            int base = 0;
            if (lane == 0 && tot) base = atomicAdd(&counts[e], tot);
            base = __shfl(base, 0);
            if (w == e) perm[e * NTOK + base + my] = tok0 + lane;
        }
    }
}

// ---------------- grouped NT GEMM: 128x256, BK=32, 3-slot ring, 2 blocks/CU ----------
// Session optimum (R10/R13-R16 verified); UP carries fused Wdown-convert blocks.
#define SLOT9 24576

template <int K, bool UP>
__global__ void __launch_bounds__(512, 2)
k_ffn9(const uint16_t* __restrict__ A, const uint16_t* __restrict__ Bw,
       const int* __restrict__ counts, const int* __restrict__ perm,
       uint16_t* __restrict__ hid_out, float* __restrict__ out,
       const float* __restrict__ cvtSrc, uint16_t* __restrict__ cvtDst) {
    constexpr int NOUT = UP ? DFF : DMODEL;
    constexpr int NT = K / 32;
    extern __shared__ char smem[];

    if constexpr (UP) {
        if (blockIdx.y >= YGEMM) {
            int chunk = ((int)(blockIdx.z * 32 + (blockIdx.y - YGEMM))) * 16 + blockIdx.x;
            const float* src = cvtSrc + (size_t)chunk * 8192 + threadIdx.x * 4;
            uint16_t*    dst = cvtDst + (size_t)chunk * 8192 + threadIdx.x * 4;
            #pragma unroll
            for (int i = 0; i < 4; ++i) {
                float4 v = *(const float4*)(src + i * 2048);
                ushort4 h;
                h.x = f2bf(v.x); h.y = f2bf(v.y); h.z = f2bf(v.z); h.w = f2bf(v.w);
                *(ushort4*)(dst + i * 2048) = h;
            }
            return;
        }
    }

    const int e = blockIdx.z;
    const int c0 = counts[0], c1 = counts[1], c2 = counts[2];
    const int cnt = counts[e];
    const int cofs = (e > 0 ? c0 : 0) + (e > 1 ? c1 : 0) + (e > 2 ? c2 : 0);
    const int base = blockIdx.y * 128;
    if (base >= cnt) return;
    const int bn0 = blockIdx.x * 256;
    const int tid = threadIdx.x;
    const int lane = tid & 63, wid = tid >> 6;
    const int wr = wid >> 2, wc = wid & 3;        // 2M x 4N, per-wave 64x64
    const int* permE = perm + e * NTOK;

    const int srow = tid >> 2;                    // 0..127
    const int sg   = (tid & 3) ^ ((tid >> 3) & 3);
    const uint16_t* gA;
    {
        int rr = base + srow;
        if constexpr (UP) {
            int tok = permE[(rr < cnt) ? rr : base];
            gA = A + (size_t)tok * K + sg * 8;
        } else {
            gA = A + (size_t)(cofs + rr) * K + sg * 8;
        }
    }
    const uint16_t* gB[2];
    #pragma unroll
    for (int j = 0; j < 2; ++j)
        gB[j] = Bw + ((size_t)e * NOUT + bn0 + j * 128 + srow) * K + sg * 8;

    const int ldsA = wid * 1024;
    const int ldsB = 8192 + wid * 1024;

    const int pg  = (lane >> 4) ^ (((lane & 15) >> 1) & 3);
    const int Aoff = (wr * 64 + (lane & 15)) * 64 + pg * 16;          // + m*1024
    const int Boff = 8192 + (wc * 64 + (lane & 15)) * 64 + pg * 16;   // + n*1024

    f32x4 acc[4][4];
    #pragma unroll
    for (int m = 0; m < 4; ++m)
        #pragma unroll
        for (int n = 0; n < 4; ++n) acc[m][n] = (f32x4){0.f, 0.f, 0.f, 0.f};

    #pragma unroll
    for (int tt = 0; tt < 2; ++tt) {
        STG(gA + tt * 32,    tt * SLOT9 + ldsA);
        STG(gB[0] + tt * 32, tt * SLOT9 + ldsB);
        STG(gB[1] + tt * 32, tt * SLOT9 + ldsB + 8192);
    }
    asm volatile("s_waitcnt vmcnt(3)" ::: "memory");
    __builtin_amdgcn_sched_barrier(0);
    __builtin_amdgcn_s_barrier();

    int cs = 0;
    #pragma unroll 1
    for (int t = 0; t < NT; ++t) {
        const char* sp = smem + cs * SLOT9;
        const bool pre = (t + 2) < NT;
        const int ss = ((cs == 0) ? 2 : cs - 1) * SLOT9;

        bf16x8 aF[4], bF[4];
        #pragma unroll
        for (int m = 0; m < 4; ++m) aF[m] = *(const bf16x8*)(sp + Aoff + m * 1024);
        #pragma unroll
        for (int n = 0; n < 4; ++n) bF[n] = *(const bf16x8*)(sp + Boff + n * 1024);
        if (pre) {
            STG(gA + (t + 2) * 32,    ss + ldsA);
            STG(gB[0] + (t + 2) * 32, ss + ldsB);
            STG(gB[1] + (t + 2) * 32, ss + ldsB + 8192);
        }
        __builtin_amdgcn_s_barrier();
        asm volatile("s_waitcnt lgkmcnt(0)" ::: "memory");
        __builtin_amdgcn_sched_barrier(0);
        __builtin_amdgcn_s_setprio(1);
        #pragma unroll
        for (int m = 0; m < 4; ++m)
            #pragma unroll
            for (int n = 0; n < 4; ++n)
                acc[m][n] = __builtin_amdgcn_mfma_f32_16x16x32_bf16(aF[m], bF[n], acc[m][n], 0, 0, 0);
        __builtin_amdgcn_s_setprio(0);
        if (pre) { asm volatile("s_waitcnt vmcnt(3)" ::: "memory"); }
        else     { asm volatile("s_waitcnt vmcnt(0)" ::: "memory"); }
        __builtin_amdgcn_sched_barrier(0);
        __builtin_amdgcn_s_barrier();
        cs = (cs == 2) ? 0 : cs + 1;
    }

    // epilogue: r = wr*64 + m*16 + (lane>>4)*4 + i, c = wc*64 + n*16 + (lane&15)
    #pragma unroll
    for (int m = 0; m < 4; ++m) {
        #pragma unroll
        for (int i = 0; i < 4; ++i) {
            int r  = wr * 64 + m * 16 + (lane >> 4) * 4 + i;
            int rr = base + r;
            if (rr < cnt) {
                if constexpr (UP) {
                    uint16_t* hr = hid_out + (size_t)(cofs + rr) * DFF + bn0 + wc * 64;
                    #pragma unroll
                    for (int n = 0; n < 4; ++n) {
                        float v = acc[m][n][i];
                        v = v > 0.f ? v : 0.f;
                        hr[n * 16 + (lane & 15)] = f2bf(v);
                    }
                } else {
                    float* orow = out + (size_t)permE[rr] * DMODEL + bn0 + wc * 64;
                    #pragma unroll
                    for (int n = 0; n < 4; ++n)
                        orow[n * 16 + (lane & 15)] = acc[m][n][i];
                }
            }
        }
    }
}

extern "C" void kernel_launch(void* const* d_in, const int* in_sizes, int n_in,
                              void* d_out, int out_size, void* d_ws, size_t ws_size,
                              hipStream_t stream) {
    const float* x     = (const float*)d_in[0];
    const float* Wup   = (const float*)d_in[1];
    const float* Wdown = (const float*)d_in[2];
    float* out  = (float*)d_out;
    float* gate = out + (size_t)NTOK * DMODEL;

    char* ws = (char*)d_ws;
    size_t off = 0;
    auto alloc = [&](size_t bytes) -> void* {
        void* p = ws + off;
        off += (bytes + 255) & ~(size_t)255;
        return p;
    };
    int*      counts  = (int*)alloc(NTILES * sizeof(int));
    float*    sig     = (float*)alloc((size_t)NTILES * DMODEL * sizeof(float));
    double*   partial = (double*)alloc((size_t)64 * NTILES * DMODEL * sizeof(double));
    int*      perm    = (int*)alloc((size_t)NTILES * NTOK * sizeof(int));
    uint16_t* xb      = (uint16_t*)alloc((size_t)NTOK * DMODEL * 2);
    uint16_t* wupb    = (uint16_t*)alloc((size_t)NTILES * DFF * DMODEL * 2);
    uint16_t* wdownb  = (uint16_t*)alloc((size_t)NTILES * DMODEL * DFF * 2);
    uint16_t* hidden  = (uint16_t*)alloc(((size_t)NTOK + 1024) * DFF * 2);
    if (off > ws_size) return;

    hipFuncSetAttribute((const void*)&k_ffn9<DMODEL, true>,
                        hipFuncAttributeMaxDynamicSharedMemorySize, 3 * SLOT9);
    hipFuncSetAttribute((const void*)&k_ffn9<DFF, false>,
                        hipFuncAttributeMaxDynamicSharedMemorySize, 3 * SLOT9);

    hipLaunchKernelGGL(k_sig, dim3(64, 4), dim3(256), 0, stream, Wup, partial);
    hipLaunchKernelGGL(k_sigfin, dim3(16), dim3(256), 0, stream, partial, sig, counts);
    // route (256 blocks, 64 tok each) + fused Wup->bf16 convert (1024 blocks)
    hipLaunchKernelGGL(k_route, dim3(1280), dim3(256), 0, stream,
                       x, sig, xb, gate, counts, perm, Wup, wupb);
    // UP GEMM + fused Wdown convert (y in [128,160) -> 4z*32*16x = 2048 chunks)
    hipLaunchKernelGGL((k_ffn9<DMODEL, true>), dim3(DFF / 256, YGEMM + 32, NTILES),
                       dim3(512), 3 * SLOT9, stream, xb, wupb, counts, perm, hidden, nullptr,
                       Wdown, wdownb);
    hipLaunchKernelGGL((k_ffn9<DFF, false>), dim3(DMODEL / 256, YGEMM, NTILES),
                       dim3(512), 3 * SLOT9, stream, hidden, wdownb, counts, perm, nullptr, out,
                       nullptr, nullptr);
}

// Round 19
// 425.342 us; speedup vs baseline: 1.0432x; 1.0153x over previous
//
#include <hip/hip_runtime.h>
#include <hip/hip_bf16.h>
#include <stdint.h>

#define NTILES 4
#define DMODEL 1024
#define DFF    4096
#define NTOK   16384
#define YGEMM  128      // UP grid: y<128 GEMM, y>=128 Wdown-convert chunks

typedef __bf16 bf16x8 __attribute__((ext_vector_type(8)));
typedef float  f32x4  __attribute__((ext_vector_type(4)));

__device__ __forceinline__ uint16_t f2bf(float f) {
    union { float f; uint32_t u; } v; v.f = f;
    uint32_t u = v.u;
    uint32_t r = (u + 0x7fffu + ((u >> 16) & 1u)) >> 16;
    return (uint16_t)r;
}

#define STG(gptr, ldsoff) __builtin_amdgcn_global_load_lds( \
    (__attribute__((address_space(1))) void*)(gptr), \
    (__attribute__((address_space(3))) void*)(smem + (ldsoff)), 16, 0, 0)

// ---------------- lean signature reduction: Wup column partial sums ----------------
__global__ void k_sig(const float* __restrict__ Wup, double* __restrict__ partial) {
    int e = blockIdx.y, fb = blockIdx.x, tid = threadIdx.x;
    const float* src = Wup + (size_t)e * DFF * DMODEL + (size_t)fb * 64 * DMODEL + tid * 4;
    double s0 = 0, s1 = 0, s2 = 0, s3 = 0;
    #pragma unroll 4
    for (int i = 0; i < 64; ++i) {
        float4 v = *(const float4*)(src + (size_t)i * DMODEL);
        s0 += v.x; s1 += v.y; s2 += v.z; s3 += v.w;
    }
    double* p = partial + (size_t)fb * (NTILES * DMODEL) + e * DMODEL + tid * 4;
    p[0] = s0; p[1] = s1; p[2] = s2; p[3] = s3;
}

// signature finalize (coalesced) + zero expert counts
__global__ void k_sigfin(const double* __restrict__ partial, float* __restrict__ sig,
                         int* __restrict__ counts) {
    int gid = blockIdx.x * 256 + threadIdx.x;    // 0..4095
    double s = 0.0;
    #pragma unroll 8
    for (int fb = 0; fb < 64; ++fb) s += partial[(size_t)fb * (NTILES * DMODEL) + gid];
    sig[gid] = (s > 0.0) ? 1.0f : ((s < 0.0) ? -1.0f : 0.0f);
    if (gid < NTILES) counts[gid] = 0;
}

// ---------------- routing: 64 tok/block, 4 atomics/block (ballot prefix) ----------------
// blockIdx.x < 256: route; >= 256: Wup->bf16 convert chunk (streams overlap).
__global__ void __launch_bounds__(256) k_route(const float* __restrict__ x,
                                               const float* __restrict__ sig,
                                               uint16_t* __restrict__ xb,
                                               float* __restrict__ gate_out,
                                               int* __restrict__ counts,
                                               int* __restrict__ perm,
                                               const float* __restrict__ Wup,
                                               uint16_t* __restrict__ wupb) {
    if (blockIdx.x >= NTOK / 64) {
        int cb = blockIdx.x - NTOK / 64;         // 0..1023, 16384 elems each
        const float* src = Wup + (size_t)cb * 16384 + threadIdx.x * 4;
        uint16_t*    dst = wupb + (size_t)cb * 16384 + threadIdx.x * 4;
        #pragma unroll 4
        for (int i = 0; i < 16; ++i) {
            float4 v = *(const float4*)(src + i * 1024);
            ushort4 h;
            h.x = f2bf(v.x); h.y = f2bf(v.y); h.z = f2bf(v.z); h.w = f2bf(v.w);
            *(ushort4*)(dst + i * 1024) = h;
        }
        return;
    }
    __shared__ float sl[NTILES * DMODEL];
    __shared__ int winners[64];
    for (int i = threadIdx.x; i < NTILES * DMODEL; i += 256) sl[i] = sig[i];
    __syncthreads();
    int wave = threadIdx.x >> 6, lane = threadIdx.x & 63;
    #pragma unroll 1
    for (int tk = 0; tk < 16; ++tk) {
        int ti  = wave * 16 + tk;
        int tok = blockIdx.x * 64 + ti;
        const float* xr = x + (size_t)tok * DMODEL;
        float sc[NTILES] = {0.f, 0.f, 0.f, 0.f};
        for (int q = 0; q < 4; ++q) {
            int c = q * 256 + lane * 4;
            float4 xv = *(const float4*)(xr + c);
            #pragma unroll
            for (int t = 0; t < NTILES; ++t) {
                const float* st = sl + t * DMODEL + c;
                sc[t] += xv.x * st[0] + xv.y * st[1] + xv.z * st[2] + xv.w * st[3];
            }
            ushort4 h;
            h.x = f2bf(xv.x); h.y = f2bf(xv.y); h.z = f2bf(xv.z); h.w = f2bf(xv.w);
            *(ushort4*)(xb + (size_t)tok * DMODEL + c) = h;
        }
        #pragma unroll
        for (int t = 0; t < NTILES; ++t)
            for (int off = 32; off; off >>= 1) sc[t] += __shfl_xor(sc[t], off);
        int w = 0; float best = sc[0];
        if (sc[1] > best) { best = sc[1]; w = 1; }
        if (sc[2] > best) { best = sc[2]; w = 2; }
        if (sc[3] > best) { best = sc[3]; w = 3; }
        if (lane < NTILES) gate_out[(size_t)tok * NTILES + lane] = (lane == w) ? 1.0f : 0.0f;
        if (lane == 0) winners[ti] = w;
    }
    __syncthreads();
    if (wave == 0) {
        int w = winners[lane];
        int tok0 = blockIdx.x * 64;
        #pragma unroll
        for (int e = 0; e < NTILES; ++e) {
            unsigned long long m = __ballot(w == e);
            int my  = __popcll(m & ((1ull << lane) - 1ull));
            int tot = __popcll(m);
            int base = 0;
            if (lane == 0 && tot) base = atomicAdd(&counts[e], tot);
            base = __shfl(base, 0);
            if (w == e) perm[e * NTOK + base + my] = tok0 + lane;
        }
    }
}

// ---------------- grouped NT GEMM: 128x256, BK=32, 3-slot ring, 2 blocks/CU ----------
// R16/R18 session optimum, with the redundant mid-iteration barrier removed:
// 3-slot ring separates every LDS overwrite from its last readers by >=1
// end-of-iter barrier (STG(t+2) targets slot (t-1)%3, read in iter t-1 and
// drained by each wave's lgkmcnt(0) before that iter's closing barrier), so
// ONE barrier per K-tile is sufficient — waves may skew within an iteration,
// overlapping one wave's MFMA with another's ds_read issue.
#define SLOT9 24576

template <int K, bool UP>
__global__ void __launch_bounds__(512, 2)
k_ffn9(const uint16_t* __restrict__ A, const uint16_t* __restrict__ Bw,
       const int* __restrict__ counts, const int* __restrict__ perm,
       uint16_t* __restrict__ hid_out, float* __restrict__ out,
       const float* __restrict__ cvtSrc, uint16_t* __restrict__ cvtDst) {
    constexpr int NOUT = UP ? DFF : DMODEL;
    constexpr int NT = K / 32;
    extern __shared__ char smem[];

    if constexpr (UP) {
        if (blockIdx.y >= YGEMM) {
            int chunk = ((int)(blockIdx.z * 32 + (blockIdx.y - YGEMM))) * 16 + blockIdx.x;
            const float* src = cvtSrc + (size_t)chunk * 8192 + threadIdx.x * 4;
            uint16_t*    dst = cvtDst + (size_t)chunk * 8192 + threadIdx.x * 4;
            #pragma unroll
            for (int i = 0; i < 4; ++i) {
                float4 v = *(const float4*)(src + i * 2048);
                ushort4 h;
                h.x = f2bf(v.x); h.y = f2bf(v.y); h.z = f2bf(v.z); h.w = f2bf(v.w);
                *(ushort4*)(dst + i * 2048) = h;
            }
            return;
        }
    }

    const int e = blockIdx.z;
    const int c0 = counts[0], c1 = counts[1], c2 = counts[2];
    const int cnt = counts[e];
    const int cofs = (e > 0 ? c0 : 0) + (e > 1 ? c1 : 0) + (e > 2 ? c2 : 0);
    const int base = blockIdx.y * 128;
    if (base >= cnt) return;
    const int bn0 = blockIdx.x * 256;
    const int tid = threadIdx.x;
    const int lane = tid & 63, wid = tid >> 6;
    const int wr = wid >> 2, wc = wid & 3;        // 2M x 4N, per-wave 64x64
    const int* permE = perm + e * NTOK;

    const int srow = tid >> 2;                    // 0..127
    const int sg   = (tid & 3) ^ ((tid >> 3) & 3);
    const uint16_t* gA;
    {
        int rr = base + srow;
        if constexpr (UP) {
            int tok = permE[(rr < cnt) ? rr : base];
            gA = A + (size_t)tok * K + sg * 8;
        } else {
            gA = A + (size_t)(cofs + rr) * K + sg * 8;
        }
    }
    const uint16_t* gB[2];
    #pragma unroll
    for (int j = 0; j < 2; ++j)
        gB[j] = Bw + ((size_t)e * NOUT + bn0 + j * 128 + srow) * K + sg * 8;

    const int ldsA = wid * 1024;
    const int ldsB = 8192 + wid * 1024;

    const int pg  = (lane >> 4) ^ (((lane & 15) >> 1) & 3);
    const int Aoff = (wr * 64 + (lane & 15)) * 64 + pg * 16;          // + m*1024
    const int Boff = 8192 + (wc * 64 + (lane & 15)) * 64 + pg * 16;   // + n*1024

    f32x4 acc[4][4];
    #pragma unroll
    for (int m = 0; m < 4; ++m)
        #pragma unroll
        for (int n = 0; n < 4; ++n) acc[m][n] = (f32x4){0.f, 0.f, 0.f, 0.f};

    #pragma unroll
    for (int tt = 0; tt < 2; ++tt) {
        STG(gA + tt * 32,    tt * SLOT9 + ldsA);
        STG(gB[0] + tt * 32, tt * SLOT9 + ldsB);
        STG(gB[1] + tt * 32, tt * SLOT9 + ldsB + 8192);
    }
    asm volatile("s_waitcnt vmcnt(3)" ::: "memory");
    __builtin_amdgcn_sched_barrier(0);
    __builtin_amdgcn_s_barrier();

    int cs = 0;
    #pragma unroll 1
    for (int t = 0; t < NT; ++t) {
        const char* sp = smem + cs * SLOT9;
        const bool pre = (t + 2) < NT;
        const int ss = ((cs == 0) ? 2 : cs - 1) * SLOT9;

        bf16x8 aF[4], bF[4];
        #pragma unroll
        for (int m = 0; m < 4; ++m) aF[m] = *(const bf16x8*)(sp + Aoff + m * 1024);
        #pragma unroll
        for (int n = 0; n < 4; ++n) bF[n] = *(const bf16x8*)(sp + Boff + n * 1024);
        if (pre) {
            STG(gA + (t + 2) * 32,    ss + ldsA);
            STG(gB[0] + (t + 2) * 32, ss + ldsB);
            STG(gB[1] + (t + 2) * 32, ss + ldsB + 8192);
        }
        // (mid-iteration barrier removed — see header comment for the proof)
        asm volatile("s_waitcnt lgkmcnt(0)" ::: "memory");
        __builtin_amdgcn_sched_barrier(0);
        __builtin_amdgcn_s_setprio(1);
        #pragma unroll
        for (int m = 0; m < 4; ++m)
            #pragma unroll
            for (int n = 0; n < 4; ++n)
                acc[m][n] = __builtin_amdgcn_mfma_f32_16x16x32_bf16(aF[m], bF[n], acc[m][n], 0, 0, 0);
        __builtin_amdgcn_s_setprio(0);
        if (pre) { asm volatile("s_waitcnt vmcnt(3)" ::: "memory"); }
        else     { asm volatile("s_waitcnt vmcnt(0)" ::: "memory"); }
        __builtin_amdgcn_sched_barrier(0);
        __builtin_amdgcn_s_barrier();
        cs = (cs == 2) ? 0 : cs + 1;
    }

    // epilogue: r = wr*64 + m*16 + (lane>>4)*4 + i, c = wc*64 + n*16 + (lane&15)
    #pragma unroll
    for (int m = 0; m < 4; ++m) {
        #pragma unroll
        for (int i = 0; i < 4; ++i) {
            int r  = wr * 64 + m * 16 + (lane >> 4) * 4 + i;
            int rr = base + r;
            if (rr < cnt) {
                if constexpr (UP) {
                    uint16_t* hr = hid_out + (size_t)(cofs + rr) * DFF + bn0 + wc * 64;
                    #pragma unroll
                    for (int n = 0; n < 4; ++n) {
                        float v = acc[m][n][i];
                        v = v > 0.f ? v : 0.f;
                        hr[n * 16 + (lane & 15)] = f2bf(v);
                    }
                } else {
                    float* orow = out + (size_t)permE[rr] * DMODEL + bn0 + wc * 64;
                    #pragma unroll
                    for (int n = 0; n < 4; ++n)
                        orow[n * 16 + (lane & 15)] = acc[m][n][i];
                }
            }
        }
    }
}

extern "C" void kernel_launch(void* const* d_in, const int* in_sizes, int n_in,
                              void* d_out, int out_size, void* d_ws, size_t ws_size,
                              hipStream_t stream) {
    const float* x     = (const float*)d_in[0];
    const float* Wup   = (const float*)d_in[1];
    const float* Wdown = (const float*)d_in[2];
    float* out  = (float*)d_out;
    float* gate = out + (size_t)NTOK * DMODEL;

    char* ws = (char*)d_ws;
    size_t off = 0;
    auto alloc = [&](size_t bytes) -> void* {
        void* p = ws + off;
        off += (bytes + 255) & ~(size_t)255;
        return p;
    };
    int*      counts  = (int*)alloc(NTILES * sizeof(int));
    float*    sig     = (float*)alloc((size_t)NTILES * DMODEL * sizeof(float));
    double*   partial = (double*)alloc((size_t)64 * NTILES * DMODEL * sizeof(double));
    int*      perm    = (int*)alloc((size_t)NTILES * NTOK * sizeof(int));
    uint16_t* xb      = (uint16_t*)alloc((size_t)NTOK * DMODEL * 2);
    uint16_t* wupb    = (uint16_t*)alloc((size_t)NTILES * DFF * DMODEL * 2);
    uint16_t* wdownb  = (uint16_t*)alloc((size_t)NTILES * DMODEL * DFF * 2);
    uint16_t* hidden  = (uint16_t*)alloc(((size_t)NTOK + 1024) * DFF * 2);
    if (off > ws_size) return;

    hipFuncSetAttribute((const void*)&k_ffn9<DMODEL, true>,
                        hipFuncAttributeMaxDynamicSharedMemorySize, 3 * SLOT9);
    hipFuncSetAttribute((const void*)&k_ffn9<DFF, false>,
                        hipFuncAttributeMaxDynamicSharedMemorySize, 3 * SLOT9);

    hipLaunchKernelGGL(k_sig, dim3(64, 4), dim3(256), 0, stream, Wup, partial);
    hipLaunchKernelGGL(k_sigfin, dim3(16), dim3(256), 0, stream, partial, sig, counts);
    // route (256 blocks, 64 tok each) + fused Wup->bf16 convert (1024 blocks)
    hipLaunchKernelGGL(k_route, dim3(1280), dim3(256), 0, stream,
                       x, sig, xb, gate, counts, perm, Wup, wupb);
    // UP GEMM + fused Wdown convert (y in [128,160) -> 4z*32*16x = 2048 chunks)
    hipLaunchKernelGGL((k_ffn9<DMODEL, true>), dim3(DFF / 256, YGEMM + 32, NTILES),
                       dim3(512), 3 * SLOT9, stream, xb, wupb, counts, perm, hidden, nullptr,
                       Wdown, wdownb);
    hipLaunchKernelGGL((k_ffn9<DFF, false>), dim3(DMODEL / 256, YGEMM, NTILES),
                       dim3(512), 3 * SLOT9, stream, hidden, wdownb, counts, perm, nullptr, out,
                       nullptr, nullptr);
}